// Round 5
// baseline (447.818 us; speedup 1.0000x reference)
//
#include <hip/hip_runtime.h>
#include <hip/hip_bf16.h>

// Problem constants (fixed by reference)
#define L_SEQ 1024
#define B_DLG 128
#define D_DIM 256
#define BM 16            // rows per block tile
#define THREADS 256      // 4 waves
#define KSTEPS 8         // 256 / 32
#define NTILES (L_SEQ / BM)             // 64 row-tiles per dialogue
#define NBLK (B_DLG * NTILES)           // 8192 blocks

typedef __attribute__((ext_vector_type(8))) short short8;   // 8 bf16 (4 VGPRs)
typedef __attribute__((ext_vector_type(4))) float f32x4;    // MFMA accumulator

__device__ __forceinline__ unsigned short f_to_bfbits(float f) {
    unsigned int u = __float_as_uint(f);
    unsigned int r = (u + 0x7FFFu + ((u >> 16) & 1u)) >> 16;   // RNE
    return (unsigned short)r;
}
__device__ __forceinline__ float fast_tanh(float x) {
    return 1.0f - 2.0f / (__expf(2.0f * x) + 1.0f);
}
__device__ __forceinline__ float fast_sigmoid(float x) {
    return 1.0f / (1.0f + __expf(-x));
}
__device__ __forceinline__ float dot4(float4 x, float4 w) {
    return x.x * w.x + x.y * w.y + x.z * w.z + x.w * w.w;
}

// Convert the three (256x256) fp32 modality weights to bf16 AND pre-arrange in
// MFMA-fragment order so the GEMM's B-loads are lane-linear (fully coalesced):
//   dst chunk (16B = 8 bf16) = ((mod*16 + cg)*8 + ks)*64 + kblk*16 + l15
//   holds src col = cg*16 + l15, k = ks*32 + kblk*8 .. +8
__global__ void wconv_kernel(const float* __restrict__ wa,
                             const float* __restrict__ wv,
                             const float* __restrict__ wl,
                             unsigned short* __restrict__ wb) {
    int i = blockIdx.x * blockDim.x + threadIdx.x;   // src chunk id, 0..24575
    int mod  = i >> 13;                              // 8192 chunks per modality
    int r    = i & 8191;                             // col*32 + ks*4 + kblk
    int col  = r >> 5;
    int ks   = (r >> 2) & 7;
    int kblk = r & 3;
    const float* src = (mod == 0) ? wa : (mod == 1) ? wv : wl;
    const float4* s = (const float4*)(src + col * 256 + ks * 32 + kblk * 8);
    float4 lo = s[0], hi = s[1];
    short8 pk;
    pk[0] = (short)f_to_bfbits(lo.x); pk[1] = (short)f_to_bfbits(lo.y);
    pk[2] = (short)f_to_bfbits(lo.z); pk[3] = (short)f_to_bfbits(lo.w);
    pk[4] = (short)f_to_bfbits(hi.x); pk[5] = (short)f_to_bfbits(hi.y);
    pk[6] = (short)f_to_bfbits(hi.z); pk[7] = (short)f_to_bfbits(hi.w);
    int dst = mod * 8192 + (((col >> 4) * 8 + ks) << 6) + kblk * 16 + (col & 15);
    *(short8*)(wb + dst * 8) = pk;
}

__global__ __launch_bounds__(THREADS, 5)
void fused_kernel(const float* __restrict__ a,
                  const float* __restrict__ v,
                  const float* __restrict__ l,
                  const unsigned short* __restrict__ wbf,   // packed fragments
                  const float* __restrict__ ba,
                  const float* __restrict__ bv,
                  const float* __restrict__ bl,
                  const float* __restrict__ wav, const float* __restrict__ bav,
                  const float* __restrict__ wal, const float* __restrict__ bal,
                  const float* __restrict__ wvl, const float* __restrict__ bvl,
                  float* __restrict__ out) {
    // LDS: 3 * 16 * 256 * 2B = 24 KiB (A tiles, XOR-swizzled) + z  -> ~25 KiB
    __shared__ __align__(16) unsigned short lds_a[3][BM][D_DIM];
    __shared__ float lds_z[3][BM];

    const int tid  = threadIdx.x;
    const int wave = tid >> 6;                    // 0..3
    const int lane = tid & 63;
    const int b    = blockIdx.x >> 6;             // dialogue 0..127
    const int t0   = (blockIdx.x & (NTILES - 1)) * BM;

    // ---- gate weights for this lane's 4 k-values (L1-hot; live in stage only) ----
    const int k0 = lane * 4;
    float4 gav0 = *(const float4*)(wav + k0);
    float4 gav1 = *(const float4*)(wav + 256 + k0);
    float4 gav2 = *(const float4*)(wav + 512 + k0);
    float4 gal0 = *(const float4*)(wal + k0);
    float4 gal1 = *(const float4*)(wal + 256 + k0);
    float4 gal2 = *(const float4*)(wal + 512 + k0);
    float4 gvl0 = *(const float4*)(wvl + k0);
    float4 gvl1 = *(const float4*)(wvl + 256 + k0);
    float4 gvl2 = *(const float4*)(wvl + 512 + k0);
    const float gbav = bav[0], gbal = bal[0], gbvl = bvl[0];

    // ---------------- stage + fused gates (one row-iteration in flight) ----------
#pragma unroll 1
    for (int i = 0; i < BM / 4; ++i) {
        const int row = wave + 4 * i;
        const size_t gbase = ((size_t)(t0 + row) * B_DLG + b) * D_DIM + lane * 4;
        float4 fa = *(const float4*)(a + gbase);
        float4 fv = *(const float4*)(v + gbase);
        float4 fl = *(const float4*)(l + gbase);

        const int boff = (lane * 8) ^ ((row & 7) << 4);
        ushort4 pa, pv, pl;
        pa.x = f_to_bfbits(fa.x); pa.y = f_to_bfbits(fa.y);
        pa.z = f_to_bfbits(fa.z); pa.w = f_to_bfbits(fa.w);
        pv.x = f_to_bfbits(fv.x); pv.y = f_to_bfbits(fv.y);
        pv.z = f_to_bfbits(fv.z); pv.w = f_to_bfbits(fv.w);
        pl.x = f_to_bfbits(fl.x); pl.y = f_to_bfbits(fl.y);
        pl.z = f_to_bfbits(fl.z); pl.w = f_to_bfbits(fl.w);
        *(ushort4*)((char*)&lds_a[0][row][0] + boff) = pa;
        *(ushort4*)((char*)&lds_a[1][row][0] + boff) = pv;
        *(ushort4*)((char*)&lds_a[2][row][0] + boff) = pl;

        float4 pav, pal, pvl;
        pav.x = fa.x * fv.x; pav.y = fa.y * fv.y; pav.z = fa.z * fv.z; pav.w = fa.w * fv.w;
        pal.x = fa.x * fl.x; pal.y = fa.y * fl.y; pal.z = fa.z * fl.z; pal.w = fa.w * fl.w;
        pvl.x = fv.x * fl.x; pvl.y = fv.y * fl.y; pvl.z = fv.z * fl.z; pvl.w = fv.w * fl.w;
        float s_av = dot4(fa, gav0) + dot4(fv, gav1) + dot4(pav, gav2);
        float s_al = dot4(fa, gal0) + dot4(fl, gal1) + dot4(pal, gal2);
        float s_vl = dot4(fv, gvl0) + dot4(fl, gvl1) + dot4(pvl, gvl2);
#pragma unroll
        for (int off = 1; off < 64; off <<= 1) {
            s_av += __shfl_xor(s_av, off);
            s_al += __shfl_xor(s_al, off);
            s_vl += __shfl_xor(s_vl, off);
        }
        if (lane == 0) {
            lds_z[0][row] = fast_sigmoid(s_av + gbav);
            lds_z[1][row] = fast_sigmoid(s_al + gbal);
            lds_z[2][row] = fast_sigmoid(s_vl + gbvl);
        }
    }
    __syncthreads();

    // ---------------- GEMM: wave owns 64 cols (4 col-tiles) x 16 rows ------------
    f32x4 acc[3][4];
#pragma unroll
    for (int m = 0; m < 3; ++m)
#pragma unroll
        for (int ct = 0; ct < 4; ++ct)
            acc[m][ct] = (f32x4){0.f, 0.f, 0.f, 0.f};

    const int l15 = lane & 15;
    const int kblk = lane >> 4;          // 0..3

#pragma unroll 2
    for (int ks = 0; ks < KSTEPS; ++ks) {
        int kbyte = ks * 64 + kblk * 16;
#pragma unroll
        for (int mod = 0; mod < 3; ++mod) {
            int bo = kbyte ^ ((l15 & 7) << 4);
            short8 afrag = *(const short8*)((const char*)&lds_a[mod][l15][0] + bo);
#pragma unroll
            for (int ct = 0; ct < 4; ++ct) {
                // packed fragment: cg = wave*4 + ct, lane-linear 1KB read
                const unsigned short* bp = wbf +
                    ((size_t)(((mod * 16 + wave * 4 + ct) * 8 + ks) * 64) + lane) * 8;
                short8 bfrag = *(const short8*)bp;
                acc[mod][ct] = __builtin_amdgcn_mfma_f32_16x16x32_bf16(
                    afrag, bfrag, acc[mod][ct], 0, 0, 0);
            }
        }
    }

    // ---------------- epilogue: tanh + gated combine + store ----------------
    const size_t rowbase = (size_t)b * L_SEQ + t0;
    const int colbase = wave * 64;
#pragma unroll
    for (int ct = 0; ct < 4; ++ct) {
        const int col = colbase + ct * 16 + l15;
        const float bba = ba[col], bbv = bv[col], bbl = bl[col];
#pragma unroll
        for (int r = 0; r < 4; ++r) {
            int rl_ = kblk * 4 + r;
            float ta = fast_tanh(acc[0][ct][r] + bba);
            float tv = fast_tanh(acc[1][ct][r] + bbv);
            float tl = fast_tanh(acc[2][ct][r] + bbl);
            float zav = lds_z[0][rl_];
            float zal = lds_z[1][rl_];
            float zvl = lds_z[2][rl_];
            float* orow = out + (rowbase + rl_) * (3 * D_DIM);
            orow[col]             = zav * ta + (1.f - zav) * tv;
            orow[D_DIM + col]     = zal * ta + (1.f - zal) * tl;
            orow[2 * D_DIM + col] = zvl * tv + (1.f - zvl) * tl;
        }
    }
}

extern "C" void kernel_launch(void* const* d_in, const int* in_sizes, int n_in,
                              void* d_out, int out_size, void* d_ws, size_t ws_size,
                              hipStream_t stream) {
    const float* a   = (const float*)d_in[0];
    const float* v   = (const float*)d_in[1];
    const float* l   = (const float*)d_in[2];
    // d_in[3] = lengths (all == L, static shape -> unused)
    const float* Wa  = (const float*)d_in[4];
    const float* ba  = (const float*)d_in[5];
    const float* Wv  = (const float*)d_in[6];
    const float* bv  = (const float*)d_in[7];
    const float* Wl  = (const float*)d_in[8];
    const float* bl  = (const float*)d_in[9];
    const float* Wav = (const float*)d_in[10];
    const float* bav = (const float*)d_in[11];
    const float* Wal = (const float*)d_in[12];
    const float* bal = (const float*)d_in[13];
    const float* Wvl = (const float*)d_in[14];
    const float* bvl = (const float*)d_in[15];
    float* out = (float*)d_out;

    unsigned short* wb = (unsigned short*)d_ws;   // needs 3*65536*2 = 384 KiB

    hipLaunchKernelGGL(wconv_kernel, dim3(96), dim3(256), 0, stream, Wa, Wv, Wl, wb);
    hipLaunchKernelGGL(fused_kernel, dim3(NBLK), dim3(THREADS), 0, stream,
                       a, v, l, wb, ba, bv, bl, Wav, bav, Wal, bal, Wvl, bvl, out);
}

// Round 6
// 247.345 us; speedup vs baseline: 1.8105x; 1.8105x over previous
//
#include <hip/hip_runtime.h>
#include <hip/hip_bf16.h>

// Problem constants (fixed by reference)
#define L_SEQ 1024
#define B_DLG 128
#define D_DIM 256
#define BM 32            // rows per block tile
#define THREADS 512      // 8 waves
#define KSTEPS 8         // 256 / 32
#define NTILES (L_SEQ / BM)             // 32 row-tiles per dialogue
#define NBLK (B_DLG * NTILES)           // 4096 blocks
#define OBPAD 778        // fp32 stride for out-staging: 4*778 % 32 == 8 (no 4-way conflict)

typedef __attribute__((ext_vector_type(8))) short short8;   // 8 bf16 (4 VGPRs)
typedef __attribute__((ext_vector_type(4))) float f32x4;    // MFMA accumulator

__device__ __forceinline__ unsigned short f_to_bfbits(float f) {
    unsigned int u = __float_as_uint(f);
    unsigned int r = (u + 0x7FFFu + ((u >> 16) & 1u)) >> 16;   // RNE
    return (unsigned short)r;
}
__device__ __forceinline__ float fast_tanh(float x) {
    return 1.0f - 2.0f / (__expf(2.0f * x) + 1.0f);
}
__device__ __forceinline__ float fast_sigmoid(float x) {
    return 1.0f / (1.0f + __expf(-x));
}
__device__ __forceinline__ float dot4(float4 x, float4 w) {
    return x.x * w.x + x.y * w.y + x.z * w.z + x.w * w.w;
}

// Convert the three (256x256) fp32 modality weights to bf16 AND pre-arrange in
// MFMA-fragment order so the GEMM's B-loads are lane-linear (fully coalesced):
//   dst chunk (16B = 8 bf16) = ((mod*16 + cg)*8 + ks)*64 + kblk*16 + l15
//   holds src col = cg*16 + l15, k = ks*32 + kblk*8 .. +8
__global__ void wconv_kernel(const float* __restrict__ wa,
                             const float* __restrict__ wv,
                             const float* __restrict__ wl,
                             unsigned short* __restrict__ wb) {
    int i = blockIdx.x * blockDim.x + threadIdx.x;   // src chunk id, 0..24575
    int mod  = i >> 13;                              // 8192 chunks per modality
    int r    = i & 8191;                             // col*32 + ks*4 + kblk
    int col  = r >> 5;
    int ks   = (r >> 2) & 7;
    int kblk = r & 3;
    const float* src = (mod == 0) ? wa : (mod == 1) ? wv : wl;
    const float4* s = (const float4*)(src + col * 256 + ks * 32 + kblk * 8);
    float4 lo = s[0], hi = s[1];
    short8 pk;
    pk[0] = (short)f_to_bfbits(lo.x); pk[1] = (short)f_to_bfbits(lo.y);
    pk[2] = (short)f_to_bfbits(lo.z); pk[3] = (short)f_to_bfbits(lo.w);
    pk[4] = (short)f_to_bfbits(hi.x); pk[5] = (short)f_to_bfbits(hi.y);
    pk[6] = (short)f_to_bfbits(hi.z); pk[7] = (short)f_to_bfbits(hi.w);
    int dst = mod * 8192 + (((col >> 4) * 8 + ks) << 6) + kblk * 16 + (col & 15);
    *(short8*)(wb + dst * 8) = pk;
}

__global__ __launch_bounds__(THREADS, 4)
void fused_kernel(const float* __restrict__ a,
                  const float* __restrict__ v,
                  const float* __restrict__ l,
                  const unsigned short* __restrict__ wbf,   // packed fragments
                  const float* __restrict__ ba,
                  const float* __restrict__ bv,
                  const float* __restrict__ bl,
                  const float* __restrict__ wav, const float* __restrict__ bav,
                  const float* __restrict__ wal, const float* __restrict__ bal,
                  const float* __restrict__ wvl, const float* __restrict__ bvl,
                  float* __restrict__ out) {
    // Union: A-tiles (3*32*256*2 = 49152 B) aliased with out-staging
    // (16*778*4 = 49792 B). A-tiles are dead by the time OB is written.
    __shared__ __align__(16) char lds_raw[16 * OBPAD * 4];
    __shared__ float lds_z[3][BM];
#define LDS_A  ((unsigned short (*)[BM][D_DIM])lds_raw)
#define LDS_OB ((float (*)[OBPAD])lds_raw)

    const int tid  = threadIdx.x;
    const int wave = tid >> 6;
    const int lane = tid & 63;
    const int b    = blockIdx.x >> 5;                  // dialogue 0..127
    const int t0   = (blockIdx.x & (NTILES - 1)) * BM; // row-tile start

    // ---------------- stage: issue ALL global loads first (MLP) ----------------
    float4 fa[4], fv[4], fl[4];
#pragma unroll
    for (int i = 0; i < BM / 8; ++i) {
        const int row = wave + 8 * i;
        const size_t gbase = ((size_t)(t0 + row) * B_DLG + b) * D_DIM + lane * 4;
        fa[i] = *(const float4*)(a + gbase);
        fv[i] = *(const float4*)(v + gbase);
        fl[i] = *(const float4*)(l + gbase);
    }

    // gate weights for this lane's 4 k-values
    const int k0 = lane * 4;
    float4 gav0 = *(const float4*)(wav + k0);
    float4 gav1 = *(const float4*)(wav + 256 + k0);
    float4 gav2 = *(const float4*)(wav + 512 + k0);
    float4 gal0 = *(const float4*)(wal + k0);
    float4 gal1 = *(const float4*)(wal + 256 + k0);
    float4 gal2 = *(const float4*)(wal + 512 + k0);
    float4 gvl0 = *(const float4*)(wvl + k0);
    float4 gvl1 = *(const float4*)(wvl + 256 + k0);
    float4 gvl2 = *(const float4*)(wvl + 512 + k0);

    // ---------------- pack -> LDS (swizzled) + fused gates ----------------
    {
        const int swz = (wave & 7) << 4;
        const int boff = (lane * 8) ^ swz;
#pragma unroll
        for (int i = 0; i < BM / 8; ++i) {
            const int row = wave + 8 * i;
            ushort4 pa, pv, pl;
            pa.x = f_to_bfbits(fa[i].x); pa.y = f_to_bfbits(fa[i].y);
            pa.z = f_to_bfbits(fa[i].z); pa.w = f_to_bfbits(fa[i].w);
            pv.x = f_to_bfbits(fv[i].x); pv.y = f_to_bfbits(fv[i].y);
            pv.z = f_to_bfbits(fv[i].z); pv.w = f_to_bfbits(fv[i].w);
            pl.x = f_to_bfbits(fl[i].x); pl.y = f_to_bfbits(fl[i].y);
            pl.z = f_to_bfbits(fl[i].z); pl.w = f_to_bfbits(fl[i].w);
            *(ushort4*)((char*)&LDS_A[0][row][0] + boff) = pa;
            *(ushort4*)((char*)&LDS_A[1][row][0] + boff) = pv;
            *(ushort4*)((char*)&LDS_A[2][row][0] + boff) = pl;

            float4 pav, pal, pvl;
            pav.x = fa[i].x * fv[i].x; pav.y = fa[i].y * fv[i].y;
            pav.z = fa[i].z * fv[i].z; pav.w = fa[i].w * fv[i].w;
            pal.x = fa[i].x * fl[i].x; pal.y = fa[i].y * fl[i].y;
            pal.z = fa[i].z * fl[i].z; pal.w = fa[i].w * fl[i].w;
            pvl.x = fv[i].x * fl[i].x; pvl.y = fv[i].y * fl[i].y;
            pvl.z = fv[i].z * fl[i].z; pvl.w = fv[i].w * fl[i].w;
            float s_av = dot4(fa[i], gav0) + dot4(fv[i], gav1) + dot4(pav, gav2);
            float s_al = dot4(fa[i], gal0) + dot4(fl[i], gal1) + dot4(pal, gal2);
            float s_vl = dot4(fv[i], gvl0) + dot4(fl[i], gvl1) + dot4(pvl, gvl2);

#pragma unroll
            for (int off = 1; off < 64; off <<= 1) {
                s_av += __shfl_xor(s_av, off);
                s_al += __shfl_xor(s_al, off);
                s_vl += __shfl_xor(s_vl, off);
            }
            if (lane == 0) {
                lds_z[0][row] = fast_sigmoid(s_av + bav[0]);
                lds_z[1][row] = fast_sigmoid(s_al + bal[0]);
                lds_z[2][row] = fast_sigmoid(s_vl + bvl[0]);
            }
        }
    }
    __syncthreads();

    // ---------------- GEMM K-loop: 3 modalities, wave owns 32 cols ----------------
    f32x4 acc[3][2][2];
#pragma unroll
    for (int m = 0; m < 3; ++m)
#pragma unroll
        for (int mt = 0; mt < 2; ++mt)
#pragma unroll
            for (int ct = 0; ct < 2; ++ct)
                acc[m][mt][ct] = (f32x4){0.f, 0.f, 0.f, 0.f};

    const int l15 = lane & 15;
    const int kblk = lane >> 4;          // 0..3
    const int colbase = wave * 32;

#pragma unroll 2
    for (int ks = 0; ks < KSTEPS; ++ks) {
        int kbyte = ks * 64 + kblk * 16;
#pragma unroll
        for (int mod = 0; mod < 3; ++mod) {
            short8 afrag[2];
#pragma unroll
            for (int mt = 0; mt < 2; ++mt) {
                int row = mt * 16 + l15;
                int bo = kbyte ^ ((row & 7) << 4);
                afrag[mt] = *(const short8*)((const char*)&LDS_A[mod][row][0] + bo);
            }
#pragma unroll
            for (int ct = 0; ct < 2; ++ct) {
                const unsigned short* bp = wbf +
                    ((size_t)(((mod * 16 + wave * 2 + ct) * 8 + ks) * 64) + lane) * 8;
                short8 bfrag = *(const short8*)bp;
#pragma unroll
                for (int mt = 0; mt < 2; ++mt)
                    acc[mod][mt][ct] = __builtin_amdgcn_mfma_f32_16x16x32_bf16(
                        afrag[mt], bfrag, acc[mod][mt][ct], 0, 0, 0);
            }
        }
    }

    // ---- hoist epilogue biases (L1-hot, but keep them out of the halves loop) ----
    const int col0 = colbase + l15, col1 = colbase + 16 + l15;
    const float bba0 = ba[col0], bba1 = ba[col1];
    const float bbv0 = bv[col0], bbv1 = bv[col1];
    const float bbl0 = bl[col0], bbl1 = bl[col1];

    // ---------------- epilogue: gate -> LDS out-stage -> wide stores ----------
    const size_t rowbase = (size_t)b * L_SEQ + t0;
#pragma unroll
    for (int half = 0; half < 2; ++half) {
        __syncthreads();   // A-tile reads (or previous OB reads) complete
        const int mt = half;
#pragma unroll
        for (int ct = 0; ct < 2; ++ct) {
            const int col = (ct == 0) ? col0 : col1;
            const float bba = (ct == 0) ? bba0 : bba1;
            const float bbv = (ct == 0) ? bbv0 : bbv1;
            const float bbl = (ct == 0) ? bbl0 : bbl1;
#pragma unroll
            for (int r = 0; r < 4; ++r) {
                const int rh = kblk * 4 + r;           // row within half
                float ta = fast_tanh(acc[0][mt][ct][r] + bba);
                float tv = fast_tanh(acc[1][mt][ct][r] + bbv);
                float tl = fast_tanh(acc[2][mt][ct][r] + bbl);
                float zav = lds_z[0][mt * 16 + rh];
                float zal = lds_z[1][mt * 16 + rh];
                float zvl = lds_z[2][mt * 16 + rh];
                LDS_OB[rh][col]             = zav * ta + (1.f - zav) * tv;
                LDS_OB[rh][D_DIM + col]     = zal * ta + (1.f - zal) * tl;
                LDS_OB[rh][2 * D_DIM + col] = zvl * tv + (1.f - zvl) * tl;
            }
        }
        __syncthreads();   // OB complete
        // wide coalesced stores: each wave-instr writes 1KB contiguous
#pragma unroll
        for (int r2 = 0; r2 < 2; ++r2) {
            const int row = wave * 2 + r2;             // 0..15 within half
#pragma unroll
            for (int s = 0; s < 3; ++s) {
                float4 val = *(const float4*)&LDS_OB[row][s * D_DIM + lane * 4];
                *(float4*)(out + (rowbase + half * 16 + row) * (3 * D_DIM)
                               + s * D_DIM + lane * 4) = val;
            }
        }
    }
#undef LDS_A
#undef LDS_OB
}

extern "C" void kernel_launch(void* const* d_in, const int* in_sizes, int n_in,
                              void* d_out, int out_size, void* d_ws, size_t ws_size,
                              hipStream_t stream) {
    const float* a   = (const float*)d_in[0];
    const float* v   = (const float*)d_in[1];
    const float* l   = (const float*)d_in[2];
    // d_in[3] = lengths (all == L, static shape -> unused)
    const float* Wa  = (const float*)d_in[4];
    const float* ba  = (const float*)d_in[5];
    const float* Wv  = (const float*)d_in[6];
    const float* bv  = (const float*)d_in[7];
    const float* Wl  = (const float*)d_in[8];
    const float* bl  = (const float*)d_in[9];
    const float* Wav = (const float*)d_in[10];
    const float* bav = (const float*)d_in[11];
    const float* Wal = (const float*)d_in[12];
    const float* bal = (const float*)d_in[13];
    const float* Wvl = (const float*)d_in[14];
    const float* bvl = (const float*)d_in[15];
    float* out = (float*)d_out;

    unsigned short* wb = (unsigned short*)d_ws;   // needs 3*65536*2 = 384 KiB

    hipLaunchKernelGGL(wconv_kernel, dim3(96), dim3(256), 0, stream, Wa, Wv, Wl, wb);
    hipLaunchKernelGGL(fused_kernel, dim3(NBLK), dim3(THREADS), 0, stream,
                       a, v, l, wb, ba, bv, bl, Wav, bav, Wal, bal, Wvl, bvl, out);
}